// Round 6
// baseline (395.532 us; speedup 1.0000x reference)
//
#include <hip/hip_runtime.h>

// Neural CDE forward, fused persistent kernel, split-f16 MFMA, transposed
// GEMMs (batch = lane&15 in MFMA D). Round-6 = round-5 structure with the
// permlane helpers fixed:
//  - ALIAS-PROOF: second swap operand produced by an opaque v_mov_b32 asm
//    copy so RA cannot coalesce both tied operands onto one physreg
//    (v_permlane16_swap_b32 v5,v5 is an in-place permute -> wrong sums).
//  - DIRECTION-PROOF: only the sum identity a'+b' = x + x[lane^N] is used
//    (holds for either swap direction). The partner-kh sum is obtained as
//    sum_xor32(hi32 ? tt : 0) -- exact, no direction assumption.
// Numerics: split-f16 (hi+lo), 3 MFMA terms per tile, f32 state everywhere.

#define NBLK 256
#define NT   512
#define RB   16
#define T_LEN 166
#define NSTEP 165
#define IC   8
#define HID  64
#define MW   128
#define NF   512

typedef _Float16 half8 __attribute__((ext_vector_type(8)));
typedef _Float16 half4 __attribute__((ext_vector_type(4)));
typedef float    f32x4 __attribute__((ext_vector_type(4)));

__device__ __forceinline__ float fast_tanh(float x) {
    float e = __expf(2.0f * x);
    return 1.0f - 2.0f * __builtin_amdgcn_rcpf(e + 1.0f);
}

__device__ __forceinline__ void bar_lgkm() {
    asm volatile("s_waitcnt lgkmcnt(0)" ::: "memory");
    __builtin_amdgcn_s_barrier();
}

// x + x[lane^16], all lanes. Works for either swap direction; b is an
// opaque copy so a/b must land in distinct physregs.
__device__ __forceinline__ float sum_xor16(float x) {
    float a = x, b;
    asm("v_mov_b32 %0, %1" : "=v"(b) : "v"(x));
    asm("v_permlane16_swap_b32 %0, %1" : "+v"(a), "+v"(b));
    return a + b;
}
// x + x[lane^32], all lanes.
__device__ __forceinline__ float sum_xor32(float x) {
    float a = x, b;
    asm("v_mov_b32 %0, %1" : "=v"(b) : "v"(x));
    asm("v_permlane32_swap_b32 %0, %1" : "+v"(a), "+v"(b));
    return a + b;
}

__global__ __launch_bounds__(NT, 2)
void cde_fused(const float* __restrict__ u0, const float* __restrict__ coeffs,
               const float* __restrict__ W1, const float* __restrict__ b1,
               const float* __restrict__ W2, const float* __restrict__ b2,
               const float* __restrict__ Wi, const float* __restrict__ bi,
               const float* __restrict__ Wr, const float* __restrict__ br,
               float* __restrict__ out)
{
    __shared__ __align__(16) unsigned char hh[RB * 256];   // h hi: 16 x 128 f16 (swizzled)
    __shared__ __align__(16) unsigned char hl[RB * 256];   // h lo
    __shared__ __align__(16) unsigned char zh[RB * 128];   // z hi: 16 x 64 f16 (swizzled)
    __shared__ __align__(16) unsigned char zl[RB * 128];   // z lo
    __shared__ float part[8][17];                          // readout partials [wave][batch]

    const int tid  = threadIdx.x;
    const int lane = tid & 63;
    const int w    = tid >> 6;      // wave 0..7
    const int l15  = lane & 15;     // batch row in MFMA D
    const int lq   = lane >> 4;     // 0..3
    const bool hi32 = (lane & 32) != 0;
    const int swzr = (l15 & 7) << 4;
    const int b0   = blockIdx.x * RB;

    // ---- stage split weights into registers/AGPRs (A-fragments of W^T) ----
    half8 w1h[2], w1l[2];
    #pragma unroll
    for (int kt = 0; kt < 2; ++kt) {
        const int krow = kt * 32 + lq * 8;
        const int ncol = w * 16 + l15;
        half8 vh, vl;
        #pragma unroll
        for (int j = 0; j < 8; ++j) {
            const float x = W1[(krow + j) * MW + ncol];
            const _Float16 hi = (_Float16)x;
            vh[j] = hi; vl[j] = (_Float16)(x - (float)hi);
        }
        w1h[kt] = vh; w1l[kt] = vl;
    }
    half8 w2h[16], w2l[16];
    #pragma unroll
    for (int q = 0; q < 4; ++q) {
        #pragma unroll
        for (int kt = 0; kt < 4; ++kt) {
            const int krow = kt * 32 + lq * 8;
            const int ncol = (w * 4 + q) * 16 + l15;
            half8 vh, vl;
            #pragma unroll
            for (int j = 0; j < 8; ++j) {
                const float x = W2[(krow + j) * NF + ncol];
                const _Float16 hi = (_Float16)x;
                vh[j] = hi; vl[j] = (_Float16)(x - (float)hi);
            }
            w2h[q * 4 + kt] = vh; w2l[q * 4 + kt] = vl;
        }
    }
    const f32x4 b1v = *(const f32x4*)(b1 + w * 16 + lq * 4);
    f32x4 b2v[4];
    #pragma unroll
    for (int q = 0; q < 4; ++q)
        b2v[q] = *(const f32x4*)(b2 + (w * 4 + q) * 16 + lq * 4);

    float wrs[8];
    #pragma unroll
    for (int j = 0; j < 8; ++j) wrs[j] = Wr[w * 8 + j];
    const float brv = br[0];

    // ---- z0: owner lane (lq==0) holds channels [8w, 8w+8) of batch l15 ----
    float z8[8];
    {
        float uu[7];
        const float* ur = u0 + (size_t)(b0 + l15) * 7;
        #pragma unroll
        for (int c = 0; c < 7; ++c) uu[c] = ur[c];
        #pragma unroll
        for (int j = 0; j < 8; ++j) {
            float a = bi[w * 8 + j];
            #pragma unroll
            for (int c = 0; c < 7; ++c) a = fmaf(uu[c], Wi[c * HID + w * 8 + j], a);
            z8[j] = a;
        }
    }
    {
        half8 hi8, lo8;
        float rp = 0.f;
        #pragma unroll
        for (int j = 0; j < 8; ++j) {
            const _Float16 hi = (_Float16)z8[j];
            hi8[j] = hi; lo8[j] = (_Float16)(z8[j] - (float)hi);
            rp = fmaf(z8[j], wrs[j], rp);
        }
        if (lq == 0) {
            const int zoff = l15 * 128 + ((w * 16) ^ swzr);
            *(half8*)(zh + zoff) = hi8;
            *(half8*)(zl + zoff) = lo8;
            part[w][l15] = rp;
        }
    }
    // per-lane coeff stream: 16B chunk (i = (lq&1)*4 .. +3) of row l15
    const float* cbase = coeffs + (size_t)(b0 + l15) * T_LEN * IC + (lq & 1) * 4;
    f32x4 ccur = *(const f32x4*)(cbase);
    __syncthreads();

    for (int t = 0; t < NSTEP; ++t) {
        const f32x4 cnext = *(const f32x4*)(cbase + (size_t)(t + 1) * IC);

        // ---- finalize out[:, t] from partials of state t (wave 7 only) ----
        if (w == 7) {
            float v = part[lq][l15] + part[lq + 4][l15];
            v = sum_xor32(sum_xor16(v));
            if (lq == 0) out[(size_t)(b0 + l15) * T_LEN + t] = v + brv;
        }

        // ---- GEMM1: h^T = W1^T @ z^T, relu, split store (dual acc) ----
        const int zo0 = l15 * 128 + ((lq * 16) ^ swzr);
        const int zo1 = l15 * 128 + ((64 + lq * 16) ^ swzr);
        const half8 zfh0 = *(const half8*)(zh + zo0);
        const half8 zfl0 = *(const half8*)(zl + zo0);
        const half8 zfh1 = *(const half8*)(zh + zo1);
        const half8 zfl1 = *(const half8*)(zl + zo1);
        f32x4 a1A = b1v;
        f32x4 a1B = {0.f, 0.f, 0.f, 0.f};
        a1A = __builtin_amdgcn_mfma_f32_16x16x32_f16(w1h[0], zfh0, a1A, 0, 0, 0);
        a1B = __builtin_amdgcn_mfma_f32_16x16x32_f16(w1h[1], zfh1, a1B, 0, 0, 0);
        a1A = __builtin_amdgcn_mfma_f32_16x16x32_f16(w1l[0], zfh0, a1A, 0, 0, 0);
        a1B = __builtin_amdgcn_mfma_f32_16x16x32_f16(w1l[1], zfh1, a1B, 0, 0, 0);
        a1A = __builtin_amdgcn_mfma_f32_16x16x32_f16(w1h[0], zfl0, a1A, 0, 0, 0);
        a1B = __builtin_amdgcn_mfma_f32_16x16x32_f16(w1h[1], zfl1, a1B, 0, 0, 0);
        half4 ph, pl;
        #pragma unroll
        for (int r = 0; r < 4; ++r) {
            const float hv = fmaxf(a1A[r] + a1B[r], 0.0f);
            const _Float16 hi = (_Float16)hv;
            ph[r] = hi; pl[r] = (_Float16)(hv - (float)hi);
        }
        const int hoff = l15 * 256 + ((w * 32 + lq * 8) ^ swzr);
        *(half4*)(hh + hoff) = ph;
        *(half4*)(hl + hoff) = pl;
        bar_lgkm();

        // ---- GEMM2 + tanh + i-contraction + register z update ----
        half8 bhf[4], blf[4];
        #pragma unroll
        for (int kt = 0; kt < 4; ++kt) {
            const int off = l15 * 256 + ((kt * 64 + lq * 16) ^ swzr);
            bhf[kt] = *(const half8*)(hh + off);
            blf[kt] = *(const half8*)(hl + off);
        }
        const f32x4 dxv = cnext - ccur;
        f32x4 accA[4], accB[4];
        #pragma unroll
        for (int q = 0; q < 4; ++q) {
            accA[q] = b2v[q];
            accB[q] = (f32x4){0.f, 0.f, 0.f, 0.f};
        }
        #pragma unroll
        for (int kt = 0; kt < 4; ++kt) {
            #pragma unroll
            for (int q = 0; q < 4; ++q) {
                accA[q] = __builtin_amdgcn_mfma_f32_16x16x32_f16(w2h[q * 4 + kt], bhf[kt], accA[q], 0, 0, 0);
                accB[q] = __builtin_amdgcn_mfma_f32_16x16x32_f16(w2l[q * 4 + kt], bhf[kt], accB[q], 0, 0, 0);
            }
        }
        #pragma unroll
        for (int kt = 0; kt < 4; ++kt) {
            #pragma unroll
            for (int q = 0; q < 4; ++q) {
                if (kt < 2) accA[q] = __builtin_amdgcn_mfma_f32_16x16x32_f16(w2h[q * 4 + kt], blf[kt], accA[q], 0, 0, 0);
                else        accB[q] = __builtin_amdgcn_mfma_f32_16x16x32_f16(w2h[q * 4 + kt], blf[kt], accB[q], 0, 0, 0);
            }
        }
        float rp = 0.f;
        #pragma unroll
        for (int q = 0; q < 4; ++q) {
            // lane (l15,lq): f-cols n=(w*4+q)*16+lq*4+r; i=(lq&1)*4+r; kh=8w+2q+(lq>>1)
            float s = 0.f;
            #pragma unroll
            for (int r = 0; r < 4; ++r)
                s = fmaf(fast_tanh(accA[q][r] + accB[q][r]), dxv[r], s);
            const float tt = sum_xor16(s);              // full i-sum of own kh
            const float uu = sum_xor32(hi32 ? tt : 0.f); // partner-kh sum on lanes<32 (exact)
            z8[2 * q]     += tt;
            z8[2 * q + 1] += uu;
            rp = fmaf(z8[2 * q], wrs[2 * q], rp);
            rp = fmaf(z8[2 * q + 1], wrs[2 * q + 1], rp);
            if (q & 1) {
                // incremental writeback of channels [4*(q>>1) .. +4)
                const int c0 = 4 * (q >> 1);
                half4 h4, l4;
                #pragma unroll
                for (int j = 0; j < 4; ++j) {
                    const float zv = z8[c0 + j];
                    const _Float16 hi = (_Float16)zv;
                    h4[j] = hi; l4[j] = (_Float16)(zv - (float)hi);
                }
                if (lq == 0) {
                    const int zoff = l15 * 128 + ((w * 16) ^ swzr) + c0 * 2;
                    *(half4*)(zh + zoff) = h4;
                    *(half4*)(zl + zoff) = l4;
                }
            }
        }
        if (lq == 0) part[w][l15] = rp;
        ccur = cnext;
        bar_lgkm();
    }

    // ---- final readout: state 165 ----
    if (w == 7) {
        float v = part[lq][l15] + part[lq + 4][l15];
        v = sum_xor32(sum_xor16(v));
        if (lq == 0) out[(size_t)(b0 + l15) * T_LEN + NSTEP] = v + brv;
    }
}

extern "C" void kernel_launch(void* const* d_in, const int* in_sizes, int n_in,
                              void* d_out, int out_size, void* d_ws, size_t ws_size,
                              hipStream_t stream) {
    const float* u0     = (const float*)d_in[0];
    const float* coeffs = (const float*)d_in[1];
    const float* W1     = (const float*)d_in[2];
    const float* b1     = (const float*)d_in[3];
    const float* W2     = (const float*)d_in[4];
    const float* b2     = (const float*)d_in[5];
    const float* Wi     = (const float*)d_in[6];
    const float* bi     = (const float*)d_in[7];
    const float* Wr     = (const float*)d_in[8];
    const float* br     = (const float*)d_in[9];
    cde_fused<<<NBLK, NT, 0, stream>>>(u0, coeffs, W1, b1, W2, b2, Wi, bi, Wr, br,
                                       (float*)d_out);
}

// Round 7
// 290.023 us; speedup vs baseline: 1.3638x; 1.3638x over previous
//
#include <hip/hip_runtime.h>

// Neural CDE forward, fused persistent kernel, split-f16 MFMA, transposed
// GEMMs (batch = lane&15 in MFMA D). Round-7 = round-4 register footprint
// (single acc per q-tile in GEMM2, full end-of-step writeback) + permlane
// cross-lane reductions via the gfx950 swap BUILTINS (clean SSA -> no
// spills; r6's asm-mov helpers caused in-loop scratch spill, WRITE_SIZE x3).
// Direction-proof: only the sum identity (r.x+r.y = x + x[lane^N]) is used;
// partner-kh sum = sum_xor32(hi32 ? tt : 0), exact on owner lanes (<32).
// Numerics: split-f16 (hi+lo), 3 MFMA terms per tile, f32 state everywhere.

#define NBLK 256
#define NT   512
#define RB   16
#define T_LEN 166
#define NSTEP 165
#define IC   8
#define HID  64
#define MW   128
#define NF   512

typedef _Float16 half8 __attribute__((ext_vector_type(8)));
typedef _Float16 half4 __attribute__((ext_vector_type(4)));
typedef float    f32x4 __attribute__((ext_vector_type(4)));

__device__ __forceinline__ float fast_tanh(float x) {
    float e = __expf(2.0f * x);
    return 1.0f - 2.0f * __builtin_amdgcn_rcpf(e + 1.0f);
}

__device__ __forceinline__ void bar_lgkm() {
    asm volatile("s_waitcnt lgkmcnt(0)" ::: "memory");
    __builtin_amdgcn_s_barrier();
    __builtin_amdgcn_sched_barrier(0);
}

// x + x[lane^16] on all lanes (swap-direction independent).
__device__ __forceinline__ float sum_xor16(float x) {
#if __has_builtin(__builtin_amdgcn_permlane16_swap)
    auto r = __builtin_amdgcn_permlane16_swap(__float_as_uint(x), __float_as_uint(x), false, false);
    return __uint_as_float(r[0]) + __uint_as_float(r[1]);
#else
    return x + __shfl_xor(x, 16, 64);
#endif
}
// x + x[lane^32] on all lanes.
__device__ __forceinline__ float sum_xor32(float x) {
#if __has_builtin(__builtin_amdgcn_permlane32_swap)
    auto r = __builtin_amdgcn_permlane32_swap(__float_as_uint(x), __float_as_uint(x), false, false);
    return __uint_as_float(r[0]) + __uint_as_float(r[1]);
#else
    return x + __shfl_xor(x, 32, 64);
#endif
}

__global__ __launch_bounds__(NT, 2)
void cde_fused(const float* __restrict__ u0, const float* __restrict__ coeffs,
               const float* __restrict__ W1, const float* __restrict__ b1,
               const float* __restrict__ W2, const float* __restrict__ b2,
               const float* __restrict__ Wi, const float* __restrict__ bi,
               const float* __restrict__ Wr, const float* __restrict__ br,
               float* __restrict__ out)
{
    __shared__ __align__(16) unsigned char hh[RB * 256];   // h hi: 16 x 128 f16 (swizzled)
    __shared__ __align__(16) unsigned char hl[RB * 256];   // h lo
    __shared__ __align__(16) unsigned char zh[RB * 128];   // z hi: 16 x 64 f16 (swizzled)
    __shared__ __align__(16) unsigned char zl[RB * 128];   // z lo
    __shared__ float part[8][17];                          // readout partials [wave][batch]

    const int tid  = threadIdx.x;
    const int lane = tid & 63;
    const int w    = tid >> 6;      // wave 0..7
    const int l15  = lane & 15;     // batch row in MFMA D
    const int lq   = lane >> 4;     // 0..3
    const bool hi32 = (lane & 32) != 0;
    const int swzr = (l15 & 7) << 4;
    const int b0   = blockIdx.x * RB;

    // ---- stage split weights into registers/AGPRs (A-fragments of W^T) ----
    half8 w1h[2], w1l[2];
    #pragma unroll
    for (int kt = 0; kt < 2; ++kt) {
        const int krow = kt * 32 + lq * 8;
        const int ncol = w * 16 + l15;
        half8 vh, vl;
        #pragma unroll
        for (int j = 0; j < 8; ++j) {
            const float x = W1[(krow + j) * MW + ncol];
            const _Float16 hi = (_Float16)x;
            vh[j] = hi; vl[j] = (_Float16)(x - (float)hi);
        }
        w1h[kt] = vh; w1l[kt] = vl;
    }
    half8 w2h[16], w2l[16];
    #pragma unroll
    for (int q = 0; q < 4; ++q) {
        #pragma unroll
        for (int kt = 0; kt < 4; ++kt) {
            const int krow = kt * 32 + lq * 8;
            const int ncol = (w * 4 + q) * 16 + l15;
            half8 vh, vl;
            #pragma unroll
            for (int j = 0; j < 8; ++j) {
                const float x = W2[(krow + j) * NF + ncol];
                const _Float16 hi = (_Float16)x;
                vh[j] = hi; vl[j] = (_Float16)(x - (float)hi);
            }
            w2h[q * 4 + kt] = vh; w2l[q * 4 + kt] = vl;
        }
    }
    const f32x4 b1v = *(const f32x4*)(b1 + w * 16 + lq * 4);
    f32x4 b2v[4];
    #pragma unroll
    for (int q = 0; q < 4; ++q)
        b2v[q] = *(const f32x4*)(b2 + (w * 4 + q) * 16 + lq * 4);

    float wrs[8];
    #pragma unroll
    for (int j = 0; j < 8; ++j) wrs[j] = Wr[w * 8 + j];
    const float brv = br[0];

    // ---- z0: owner lane (lq==0) holds channels [8w, 8w+8) of batch l15 ----
    float z8[8];
    {
        float uu[7];
        const float* ur = u0 + (size_t)(b0 + l15) * 7;
        #pragma unroll
        for (int c = 0; c < 7; ++c) uu[c] = ur[c];
        #pragma unroll
        for (int j = 0; j < 8; ++j) {
            float a = bi[w * 8 + j];
            #pragma unroll
            for (int c = 0; c < 7; ++c) a = fmaf(uu[c], Wi[c * HID + w * 8 + j], a);
            z8[j] = a;
        }
    }
    {
        half8 hi8, lo8;
        float rp = 0.f;
        #pragma unroll
        for (int j = 0; j < 8; ++j) {
            const _Float16 hi = (_Float16)z8[j];
            hi8[j] = hi; lo8[j] = (_Float16)(z8[j] - (float)hi);
            rp = fmaf(z8[j], wrs[j], rp);
        }
        if (lq == 0) {
            const int zoff = l15 * 128 + ((w * 16) ^ swzr);
            *(half8*)(zh + zoff) = hi8;
            *(half8*)(zl + zoff) = lo8;
            part[w][l15] = rp;
        }
    }
    // per-lane coeff stream: 16B chunk (i = (lq&1)*4 .. +3) of row l15
    const float* cbase = coeffs + (size_t)(b0 + l15) * T_LEN * IC + (lq & 1) * 4;
    f32x4 ccur = *(const f32x4*)(cbase);
    __syncthreads();

    for (int t = 0; t < NSTEP; ++t) {
        const f32x4 cnext = *(const f32x4*)(cbase + (size_t)(t + 1) * IC);

        // ---- finalize out[:, t] from partials of state t (wave 7 only) ----
        if (w == 7) {
            float v = part[lq][l15] + part[lq + 4][l15];
            v = sum_xor32(sum_xor16(v));
            if (lq == 0) out[(size_t)(b0 + l15) * T_LEN + t] = v + brv;
        }

        // ---- GEMM1: h^T = W1^T @ z^T, relu, split store (dual acc) ----
        const int zo0 = l15 * 128 + ((lq * 16) ^ swzr);
        const int zo1 = l15 * 128 + ((64 + lq * 16) ^ swzr);
        const half8 zfh0 = *(const half8*)(zh + zo0);
        const half8 zfl0 = *(const half8*)(zl + zo0);
        const half8 zfh1 = *(const half8*)(zh + zo1);
        const half8 zfl1 = *(const half8*)(zl + zo1);
        f32x4 a1A = b1v;
        f32x4 a1B = {0.f, 0.f, 0.f, 0.f};
        a1A = __builtin_amdgcn_mfma_f32_16x16x32_f16(w1h[0], zfh0, a1A, 0, 0, 0);
        a1B = __builtin_amdgcn_mfma_f32_16x16x32_f16(w1h[1], zfh1, a1B, 0, 0, 0);
        a1A = __builtin_amdgcn_mfma_f32_16x16x32_f16(w1l[0], zfh0, a1A, 0, 0, 0);
        a1B = __builtin_amdgcn_mfma_f32_16x16x32_f16(w1l[1], zfh1, a1B, 0, 0, 0);
        a1A = __builtin_amdgcn_mfma_f32_16x16x32_f16(w1h[0], zfl0, a1A, 0, 0, 0);
        a1B = __builtin_amdgcn_mfma_f32_16x16x32_f16(w1h[1], zfl1, a1B, 0, 0, 0);
        half4 ph, pl;
        #pragma unroll
        for (int r = 0; r < 4; ++r) {
            const float hv = fmaxf(a1A[r] + a1B[r], 0.0f);
            const _Float16 hi = (_Float16)hv;
            ph[r] = hi; pl[r] = (_Float16)(hv - (float)hi);
        }
        const int hoff = l15 * 256 + ((w * 32 + lq * 8) ^ swzr);
        *(half4*)(hh + hoff) = ph;
        *(half4*)(hl + hoff) = pl;
        bar_lgkm();

        // ---- GEMM2 + tanh + i-contraction + register z update ----
        half8 bhf[4], blf[4];
        #pragma unroll
        for (int kt = 0; kt < 4; ++kt) {
            const int off = l15 * 256 + ((kt * 64 + lq * 16) ^ swzr);
            bhf[kt] = *(const half8*)(hh + off);
            blf[kt] = *(const half8*)(hl + off);
        }
        const f32x4 dxv = cnext - ccur;
        float rp = 0.f;
        #pragma unroll
        for (int q = 0; q < 4; ++q) {
            f32x4 acc = b2v[q];
            #pragma unroll
            for (int kt = 0; kt < 4; ++kt) {
                acc = __builtin_amdgcn_mfma_f32_16x16x32_f16(w2h[q * 4 + kt], bhf[kt], acc, 0, 0, 0);
                acc = __builtin_amdgcn_mfma_f32_16x16x32_f16(w2l[q * 4 + kt], bhf[kt], acc, 0, 0, 0);
                acc = __builtin_amdgcn_mfma_f32_16x16x32_f16(w2h[q * 4 + kt], blf[kt], acc, 0, 0, 0);
            }
            // lane (l15,lq): f-cols n=(w*4+q)*16+lq*4+r; i=(lq&1)*4+r; kh=8w+2q+(lq>>1)
            float s = 0.f;
            #pragma unroll
            for (int r = 0; r < 4; ++r)
                s = fmaf(fast_tanh(acc[r]), dxv[r], s);
            const float tt = sum_xor16(s);               // full i-sum of own kh
            const float uu = sum_xor32(hi32 ? tt : 0.f); // partner-kh sum (lanes<32)
            z8[2 * q]     += tt;
            z8[2 * q + 1] += uu;
            rp = fmaf(z8[2 * q], wrs[2 * q], rp);
            rp = fmaf(z8[2 * q + 1], wrs[2 * q + 1], rp);
        }
        // ---- end-of-step writeback: 2 b128 stores + readout partial ----
        {
            half8 hi8, lo8;
            #pragma unroll
            for (int j = 0; j < 8; ++j) {
                const _Float16 hi = (_Float16)z8[j];
                hi8[j] = hi; lo8[j] = (_Float16)(z8[j] - (float)hi);
            }
            if (lq == 0) {
                const int zoff = l15 * 128 + ((w * 16) ^ swzr);
                *(half8*)(zh + zoff) = hi8;
                *(half8*)(zl + zoff) = lo8;
                part[w][l15] = rp;
            }
        }
        ccur = cnext;
        bar_lgkm();
    }

    // ---- final readout: state 165 ----
    if (w == 7) {
        float v = part[lq][l15] + part[lq + 4][l15];
        v = sum_xor32(sum_xor16(v));
        if (lq == 0) out[(size_t)(b0 + l15) * T_LEN + NSTEP] = v + brv;
    }
}

extern "C" void kernel_launch(void* const* d_in, const int* in_sizes, int n_in,
                              void* d_out, int out_size, void* d_ws, size_t ws_size,
                              hipStream_t stream) {
    const float* u0     = (const float*)d_in[0];
    const float* coeffs = (const float*)d_in[1];
    const float* W1     = (const float*)d_in[2];
    const float* b1     = (const float*)d_in[3];
    const float* W2     = (const float*)d_in[4];
    const float* b2     = (const float*)d_in[5];
    const float* Wi     = (const float*)d_in[6];
    const float* bi     = (const float*)d_in[7];
    const float* Wr     = (const float*)d_in[8];
    const float* br     = (const float*)d_in[9];
    cde_fused<<<NBLK, NT, 0, stream>>>(u0, coeffs, W1, b1, W2, b2, Wi, bi, Wr, br,
                                       (float*)d_out);
}

// Round 8
// 289.442 us; speedup vs baseline: 1.3665x; 1.0020x over previous
//
#include <hip/hip_runtime.h>

// Neural CDE forward, fused persistent kernel, split-f16 MFMA, transposed
// GEMMs. Round-8: 16-WAVE blocks (1024 thr) for 4 waves/SIMD occupancy.
//  - wave w owns 2 GEMM2 ntiles {2w, 2w+1} (was 4): w2 regs 128 -> 64.
//  - z ownership: wave w, lanes lq==0 hold channels [4w, 4w+4) of batch l15.
//  - GEMM1 on waves 0-7 (ntile w), W1 fragments staged in LDS at startup
//    (stride-80B slots, 4 ds_read_b128/step) so no wave carries w1 in regs.
//  - wave 15 finalizes the readout during the GEMM1 phase (otherwise idle).
//  - __launch_bounds__(1024,4) caps regs at 128 -> 16 waves/CU resident.
// Numerics unchanged: split-f16 (hi+lo), 3 MFMA terms per tile, f32 state.

#define NBLK 256
#define NT   1024
#define RB   16
#define T_LEN 166
#define NSTEP 165
#define IC   8
#define HID  64
#define MW   128
#define NF   512

typedef _Float16 half8 __attribute__((ext_vector_type(8)));
typedef _Float16 half4 __attribute__((ext_vector_type(4)));
typedef float    f32x4 __attribute__((ext_vector_type(4)));

__device__ __forceinline__ float fast_tanh(float x) {
    float e = __expf(2.0f * x);
    return 1.0f - 2.0f * __builtin_amdgcn_rcpf(e + 1.0f);
}

__device__ __forceinline__ void bar_lgkm() {
    asm volatile("s_waitcnt lgkmcnt(0)" ::: "memory");
    __builtin_amdgcn_s_barrier();
    __builtin_amdgcn_sched_barrier(0);
}

// x + x[lane^16] on all lanes (swap-direction independent).
__device__ __forceinline__ float sum_xor16(float x) {
#if __has_builtin(__builtin_amdgcn_permlane16_swap)
    auto r = __builtin_amdgcn_permlane16_swap(__float_as_uint(x), __float_as_uint(x), false, false);
    return __uint_as_float(r[0]) + __uint_as_float(r[1]);
#else
    return x + __shfl_xor(x, 16, 64);
#endif
}
// x + x[lane^32] on all lanes.
__device__ __forceinline__ float sum_xor32(float x) {
#if __has_builtin(__builtin_amdgcn_permlane32_swap)
    auto r = __builtin_amdgcn_permlane32_swap(__float_as_uint(x), __float_as_uint(x), false, false);
    return __uint_as_float(r[0]) + __uint_as_float(r[1]);
#else
    return x + __shfl_xor(x, 32, 64);
#endif
}

__global__ __launch_bounds__(NT, 4)
void cde_fused(const float* __restrict__ u0, const float* __restrict__ coeffs,
               const float* __restrict__ W1, const float* __restrict__ b1,
               const float* __restrict__ W2, const float* __restrict__ b2,
               const float* __restrict__ Wi, const float* __restrict__ bi,
               const float* __restrict__ Wr, const float* __restrict__ br,
               float* __restrict__ out)
{
    __shared__ __align__(16) unsigned char hh[RB * 256];    // h hi: 16 x 128 f16 (swizzled)
    __shared__ __align__(16) unsigned char hl[RB * 256];    // h lo
    __shared__ __align__(16) unsigned char zh[RB * 128];    // z hi: 16 x 64 f16 (swizzled)
    __shared__ __align__(16) unsigned char zl[RB * 128];    // z lo
    __shared__ __align__(16) unsigned char w1f[8 * 64 * 80];// W1 frags: (wave,lane) slots
    __shared__ float part[16][17];                          // readout partials [group][batch]

    const int tid  = threadIdx.x;
    const int lane = tid & 63;
    const int w    = tid >> 6;      // wave 0..15
    const int l15  = lane & 15;     // batch row in MFMA D
    const int lq   = lane >> 4;     // 0..3
    const bool hi32 = (lane & 32) != 0;
    const int swzr = (l15 & 7) << 4;
    const int b0   = blockIdx.x * RB;

    // ---- stage split W2 (2 ntiles per wave) into registers ----
    half8 w2h[8], w2l[8];
    #pragma unroll
    for (int q = 0; q < 2; ++q) {
        #pragma unroll
        for (int kt = 0; kt < 4; ++kt) {
            const int krow = kt * 32 + lq * 8;
            const int ncol = (w * 2 + q) * 16 + l15;
            half8 vh, vl;
            #pragma unroll
            for (int j = 0; j < 8; ++j) {
                const float x = W2[(krow + j) * NF + ncol];
                const _Float16 hi = (_Float16)x;
                vh[j] = hi; vl[j] = (_Float16)(x - (float)hi);
            }
            w2h[q * 4 + kt] = vh; w2l[q * 4 + kt] = vl;
        }
    }
    f32x4 b2v[2];
    #pragma unroll
    for (int q = 0; q < 2; ++q)
        b2v[q] = *(const f32x4*)(b2 + (w * 2 + q) * 16 + lq * 4);

    // ---- stage split W1 fragments into LDS (waves 0-7) ----
    f32x4 b1v = {0.f, 0.f, 0.f, 0.f};
    const int fbase = (w * 64 + lane) * 80;   // 80B slot: 4x16B frags + 16B pad
    if (w < 8) {
        #pragma unroll
        for (int kt = 0; kt < 2; ++kt) {
            const int krow = kt * 32 + lq * 8;
            const int ncol = w * 16 + l15;
            half8 vh, vl;
            #pragma unroll
            for (int j = 0; j < 8; ++j) {
                const float x = W1[(krow + j) * MW + ncol];
                const _Float16 hi = (_Float16)x;
                vh[j] = hi; vl[j] = (_Float16)(x - (float)hi);
            }
            *(half8*)(w1f + fbase + kt * 16)      = vh;   // h0 @0, h1 @16
            *(half8*)(w1f + fbase + 32 + kt * 16) = vl;   // l0 @32, l1 @48
        }
        b1v = *(const f32x4*)(b1 + w * 16 + lq * 4);
    }

    // readout weights for this wave's 4 channels (wave-uniform -> scalar)
    const int w_u = __builtin_amdgcn_readfirstlane(w);
    float wrs[4];
    #pragma unroll
    for (int j = 0; j < 4; ++j) wrs[j] = Wr[w_u * 4 + j];
    const float brv = br[0];

    // ---- z0: owner lane (lq==0) holds channels [4w, 4w+4) of batch l15 ----
    float z4[4];
    {
        float uu7[7];
        const float* ur = u0 + (size_t)(b0 + l15) * 7;
        #pragma unroll
        for (int c = 0; c < 7; ++c) uu7[c] = ur[c];
        #pragma unroll
        for (int j = 0; j < 4; ++j) {
            float a = bi[w * 4 + j];
            #pragma unroll
            for (int c = 0; c < 7; ++c) a = fmaf(uu7[c], Wi[c * HID + w * 4 + j], a);
            z4[j] = a;
        }
    }
    {
        half4 h4, l4;
        float rp = 0.f;
        #pragma unroll
        for (int j = 0; j < 4; ++j) {
            const _Float16 hi = (_Float16)z4[j];
            h4[j] = hi; l4[j] = (_Float16)(z4[j] - (float)hi);
            rp = fmaf(z4[j], wrs[j], rp);
        }
        if (lq == 0) {
            const int zoff = l15 * 128 + ((w * 8) ^ swzr);
            *(half4*)(zh + zoff) = h4;
            *(half4*)(zl + zoff) = l4;
            part[w][l15] = rp;
        }
    }
    // per-lane coeff stream: 16B chunk (i = (lq&1)*4 .. +3) of row l15
    const float* cbase = coeffs + (size_t)(b0 + l15) * T_LEN * IC + (lq & 1) * 4;
    f32x4 ccur = *(const f32x4*)(cbase);
    __syncthreads();

    for (int t = 0; t < NSTEP; ++t) {
        const f32x4 cnext = *(const f32x4*)(cbase + (size_t)(t + 1) * IC);

        // ---- readout finalize for state t (wave 15, idle in GEMM1 phase) ----
        if (w == 15) {
            float v = part[lq * 4 + 0][l15] + part[lq * 4 + 1][l15]
                    + part[lq * 4 + 2][l15] + part[lq * 4 + 3][l15];
            v = sum_xor32(sum_xor16(v));
            if (lq == 0) out[(size_t)(b0 + l15) * T_LEN + t] = v + brv;
        }

        // ---- GEMM1 (waves 0-7): h^T = W1^T @ z^T, relu, split store ----
        if (w < 8) {
            const int zo0 = l15 * 128 + ((lq * 16) ^ swzr);
            const int zo1 = l15 * 128 + ((64 + lq * 16) ^ swzr);
            half8 fh = *(const half8*)(w1f + fbase);          // h kt0
            half8 fl = *(const half8*)(w1f + fbase + 32);     // l kt0
            const half8 zfh0 = *(const half8*)(zh + zo0);
            const half8 zfl0 = *(const half8*)(zl + zo0);
            f32x4 a1A = b1v;
            a1A = __builtin_amdgcn_mfma_f32_16x16x32_f16(fh, zfh0, a1A, 0, 0, 0);
            a1A = __builtin_amdgcn_mfma_f32_16x16x32_f16(fl, zfh0, a1A, 0, 0, 0);
            a1A = __builtin_amdgcn_mfma_f32_16x16x32_f16(fh, zfl0, a1A, 0, 0, 0);
            fh = *(const half8*)(w1f + fbase + 16);           // h kt1
            fl = *(const half8*)(w1f + fbase + 48);           // l kt1
            const half8 zfh1 = *(const half8*)(zh + zo1);
            const half8 zfl1 = *(const half8*)(zl + zo1);
            a1A = __builtin_amdgcn_mfma_f32_16x16x32_f16(fh, zfh1, a1A, 0, 0, 0);
            a1A = __builtin_amdgcn_mfma_f32_16x16x32_f16(fl, zfh1, a1A, 0, 0, 0);
            a1A = __builtin_amdgcn_mfma_f32_16x16x32_f16(fh, zfl1, a1A, 0, 0, 0);
            half4 ph, pl;
            #pragma unroll
            for (int r = 0; r < 4; ++r) {
                const float hv = fmaxf(a1A[r], 0.0f);
                const _Float16 hi = (_Float16)hv;
                ph[r] = hi; pl[r] = (_Float16)(hv - (float)hi);
            }
            const int hoff = l15 * 256 + ((w * 32 + lq * 8) ^ swzr);
            *(half4*)(hh + hoff) = ph;
            *(half4*)(hl + hoff) = pl;
        }
        bar_lgkm();

        // ---- GEMM2 (all 16 waves, 2 ntiles each) ----
        f32x4 acc0 = b2v[0];
        f32x4 acc1 = b2v[1];
        #pragma unroll
        for (int kt = 0; kt < 4; ++kt) {
            const int off = l15 * 256 + ((kt * 64 + lq * 16) ^ swzr);
            const half8 bh = *(const half8*)(hh + off);
            const half8 bl = *(const half8*)(hl + off);
            acc0 = __builtin_amdgcn_mfma_f32_16x16x32_f16(w2h[kt],     bh, acc0, 0, 0, 0);
            acc1 = __builtin_amdgcn_mfma_f32_16x16x32_f16(w2h[4 + kt], bh, acc1, 0, 0, 0);
            acc0 = __builtin_amdgcn_mfma_f32_16x16x32_f16(w2l[kt],     bh, acc0, 0, 0, 0);
            acc1 = __builtin_amdgcn_mfma_f32_16x16x32_f16(w2l[4 + kt], bh, acc1, 0, 0, 0);
            acc0 = __builtin_amdgcn_mfma_f32_16x16x32_f16(w2h[kt],     bl, acc0, 0, 0, 0);
            acc1 = __builtin_amdgcn_mfma_f32_16x16x32_f16(w2h[4 + kt], bl, acc1, 0, 0, 0);
        }

        // ---- tanh + i-contraction + register z update ----
        // lane (l15,lq), q: f-cols n=(2w+q)*16+lq*4+r; i=(lq&1)*4+r; kh=4w+2q+(lq>>1)
        const f32x4 dxv = cnext - ccur;
        float s0 = 0.f, s1 = 0.f;
        #pragma unroll
        for (int r = 0; r < 4; ++r) {
            s0 = fmaf(fast_tanh(acc0[r]), dxv[r], s0);
            s1 = fmaf(fast_tanh(acc1[r]), dxv[r], s1);
        }
        {
            const float tt0 = sum_xor16(s0);
            const float uu0 = sum_xor32(hi32 ? tt0 : 0.f);
            z4[0] += tt0; z4[1] += uu0;
            const float tt1 = sum_xor16(s1);
            const float uu1 = sum_xor32(hi32 ? tt1 : 0.f);
            z4[2] += tt1; z4[3] += uu1;
        }
        // ---- writeback: 2 half4 stores + readout partial (owner lanes) ----
        {
            half4 h4, l4;
            float rp = 0.f;
            #pragma unroll
            for (int j = 0; j < 4; ++j) {
                const _Float16 hi = (_Float16)z4[j];
                h4[j] = hi; l4[j] = (_Float16)(z4[j] - (float)hi);
                rp = fmaf(z4[j], wrs[j], rp);
            }
            if (lq == 0) {
                const int zoff = l15 * 128 + ((w * 8) ^ swzr);
                *(half4*)(zh + zoff) = h4;
                *(half4*)(zl + zoff) = l4;
                part[w][l15] = rp;
            }
        }
        ccur = cnext;
        bar_lgkm();
    }

    // ---- final readout: state 165 ----
    if (w == 15) {
        float v = part[lq * 4 + 0][l15] + part[lq * 4 + 1][l15]
                + part[lq * 4 + 2][l15] + part[lq * 4 + 3][l15];
        v = sum_xor32(sum_xor16(v));
        if (lq == 0) out[(size_t)(b0 + l15) * T_LEN + NSTEP] = v + brv;
    }
}

extern "C" void kernel_launch(void* const* d_in, const int* in_sizes, int n_in,
                              void* d_out, int out_size, void* d_ws, size_t ws_size,
                              hipStream_t stream) {
    const float* u0     = (const float*)d_in[0];
    const float* coeffs = (const float*)d_in[1];
    const float* W1     = (const float*)d_in[2];
    const float* b1     = (const float*)d_in[3];
    const float* W2     = (const float*)d_in[4];
    const float* b2     = (const float*)d_in[5];
    const float* Wi     = (const float*)d_in[6];
    const float* bi     = (const float*)d_in[7];
    const float* Wr     = (const float*)d_in[8];
    const float* br     = (const float*)d_in[9];
    cde_fused<<<NBLK, NT, 0, stream>>>(u0, coeffs, W1, b1, W2, b2, Wi, bi, Wr, br,
                                       (float*)d_out);
}